// Round 7
// baseline (384.021 us; speedup 1.0000x reference)
//
#include <hip/hip_runtime.h>

#define Nn 8
#define Cc 256
#define C8 32
#define Hh 56
#define Ww 56
#define HW 3136
#define CHW (Cc * HW)          // 802816
#define K9C 2304
#define S_HW (1.0f / 56.0f)    // 1/sqrt(H*W)
#define S_C  0.0625f           // 1/sqrt(C)
#define XPLANE 3844            // 62*62 padded plane
#define XPAD_ELEMS (Nn * XPLANE * Cc)

typedef float f4 __attribute__((ext_vector_type(4)));
typedef unsigned short ushort;
typedef __attribute__((ext_vector_type(4))) unsigned short u16x4;
typedef __attribute__((ext_vector_type(8))) unsigned short u16x8;
typedef __attribute__((ext_vector_type(8))) short short8;   // bf16 MFMA frag
typedef __attribute__((ext_vector_type(4))) float floatx4;

__device__ __forceinline__ ushort f2bf(float f) {   // RNE
    union { float f; unsigned u; } v; v.f = f;
    unsigned r = v.u + 0x7FFF + ((v.u >> 16) & 1);
    return (ushort)(r >> 16);
}
__device__ __forceinline__ float bf2f(ushort u) {
    union { unsigned u; float f; } v; v.u = ((unsigned)u) << 16;
    return v.f;
}

// ---- fused: t3 = (p2*x)^2 (bf16 out) + t5 = softmax_h(roll(t3,+1h,-1w)) (bf16)
__global__ __launch_bounds__(256) void k_t3sm(const float* __restrict__ x,
                                              const float* __restrict__ p2,
                                              ushort* __restrict__ t3b,
                                              ushort* __restrict__ t5b) {
    __shared__ float ld[HW];
    __shared__ float mx[Ww], rs[Ww];
    int tid = threadIdx.x;
    int nc = blockIdx.x;                 // n*C + c
    int c = nc & 255;
    const float* xn = x + (size_t)nc * HW;
    const float* pp = p2 + (size_t)c * HW;
    ushort* t3n = t3b + (size_t)nc * HW;
    for (int i = tid; i < 784; i += 256) {
        f4 xv = *(const f4*)(xn + i * 4);
        f4 pv = *(const f4*)(pp + i * 4);
        f4 t = xv * pv;
        f4 q = t * t;
        *(f4*)(&ld[i * 4]) = q;
        u16x4 qb = { f2bf(q[0]), f2bf(q[1]), f2bf(q[2]), f2bf(q[3]) };
        *(u16x4*)(t3n + i * 4) = qb;
    }
    __syncthreads();
    if (tid < Ww) {
        float m = -1e30f;
        for (int h = 0; h < Hh; h++) m = fmaxf(m, ld[h * Ww + tid]);
        float s = 0.f;
        for (int h = 0; h < Hh; h++) s += __expf(ld[h * Ww + tid] - m);
        mx[tid] = m;
        rs[tid] = 1.0f / s;
    }
    __syncthreads();
    ushort* dst = t5b + (size_t)nc * HW;
    for (int i = tid; i < HW; i += 256) {
        int h = i / Ww, w = i - h * Ww;
        int wp = (w + 1 == Ww) ? 0 : w + 1;
        int hp = (h == 0) ? Hh - 1 : h - 1;
        dst[i] = f2bf(__expf(ld[hp * Ww + wp] - mx[wp]) * rs[wp]);
    }
}

// ------- xpT[n][(h+3)*62+(w+3)][c] = bf16(x[n][c][h][w])  (padded transpose)
__global__ __launch_bounds__(256) void k_xT(const float* __restrict__ x,
                                            ushort* __restrict__ xpT) {
    __shared__ ushort Ts[112][40];
    int tid = threadIdx.x;
    int n = blockIdx.z;
    int c0 = blockIdx.y * 32;
    int s0 = blockIdx.x * 112;          // 2 exact h-rows
    const float* xn = x + (size_t)n * CHW;
#pragma unroll
    for (int e = 0; e < 4; e++) {
        int lin = tid + e * 256;
        int sq = lin & 31;
        int c_l = lin >> 5;
        if (sq < 28) {
            f4 v = *(const f4*)(xn + (size_t)(c0 + c_l) * HW + s0 + sq * 4);
#pragma unroll
            for (int k = 0; k < 4; k++) Ts[sq * 4 + k][c_l] = f2bf(v[k]);
        }
    }
    __syncthreads();
    ushort* dstn = xpT + (size_t)n * (XPLANE * Cc);
#pragma unroll
    for (int e = 0; e < 2; e++) {
        int lin = tid + e * 256;
        int r = lin >> 2, ch = lin & 3;
        if (r < 112) {
            u16x8 v = *(const u16x8*)(&Ts[r][ch * 8]);
            int s_g = s0 + r;
            int h = s_g / 56;
            int wc = s_g - h * 56;
            size_t drow = (size_t)((h + 3) * 62 + wc + 3);
            *(u16x8*)(dstn + drow * Cc + c0 + ch * 8) = v;
        }
    }
}

// -------- merged prep: w7p permute + w15/p16 bf16 converts
__global__ __launch_bounds__(256) void k_prep(const float* __restrict__ w7,
                                              const float* __restrict__ w15,
                                              const float* __restrict__ p16,
                                              ushort* __restrict__ w7p,
                                              ushort* __restrict__ w15b,
                                              ushort* __restrict__ p16b) {
    int g = blockIdx.x * 256 + threadIdx.x;
    if (g < 589824) {                    // w7p[ij][o][c] = w7[o][c*9+ij]
        int ij = g >> 16;
        int rem = g & 65535;
        int o = rem >> 8;
        int c = rem & 255;
        w7p[g] = f2bf(w7[(size_t)o * K9C + c * 9 + ij]);
    } else if (g < 655360) {
        int i = g - 589824;
        w15b[i] = f2bf(w15[i]);
    } else {
        int i = g - 655360;
        if (i < 802816) p16b[i] = f2bf(p16[i]);
    }
}

// --------------- t7b = bf16(w7 @ im2col(x)) as 9 shifted GEMMs over xpT
// Bs: stride-32 rows + chunk XOR swizzle by (row>>1)&3 — staging writes
// conflict-free, reads 2-way (free). A-loads software-pipelined over ij.
__global__ __launch_bounds__(256, 3) void k_gemm_t7_mfma(
        const ushort* __restrict__ xpT,
        const ushort* __restrict__ w7p,
        ushort* __restrict__ t7b) {
    __shared__ __align__(16) ushort Bs[620 * 32];
    int tid = threadIdx.x;
    int lane = tid & 63;
    int ln15 = lane & 15, quad = lane >> 4;
    int wave = tid >> 6;
    int wo = (wave >> 1) * 32;
    int wsx = (wave & 1) * 112;
    int n = blockIdx.z;
    int hb = blockIdx.y;                 // 0..13
    int o0 = blockIdx.x * 64;
    const ushort* stagePtr = xpT + (size_t)n * (XPLANE * Cc) + (size_t)(hb * 248) * Cc;

    int sp0[7];
#pragma unroll
    for (int f = 0; f < 7; f++) {
        int s_l = wsx + f * 16 + ln15;
        int orow = s_l / 56;
        int wv = s_l - orow * 56;
        sp0[f] = orow * 62 + wv;
    }

    const ushort* wbase = w7p + (size_t)(o0 + wo + ln15) * Cc + quad * 8;
    // A(ij, ct, m) at wbase + ij*256*Cc + m*16*Cc + ct
#define ALOAD(ij, ct, m) (*(const short8*)(wbase + (size_t)(ij) * (256 * Cc) + (m) * (16 * Cc) + (ct)))

    floatx4 acc[2][7] = {};
    short8 ca0 = ALOAD(0, 0, 0);
    short8 ca1 = ALOAD(0, 0, 1);

    for (int ct = 0; ct < Cc; ct += 32) {
        __syncthreads();                 // Bs safe to overwrite
#pragma unroll
        for (int e = 0; e < 10; e++) {
            int lin = tid + e * 256;
            if (lin < 2480) {
                int row = lin >> 2, ch = lin & 3;
                u16x8 v = *(const u16x8*)(stagePtr + (size_t)row * Cc + ct + ch * 8);
                *(u16x8*)(&Bs[row * 32 + ((ch ^ ((row >> 1) & 3)) << 3)]) = v;
            }
        }
        __syncthreads();
#pragma unroll
        for (int ij = 0; ij < 9; ij++) {
            int dsp = (ij / 3) * 186 + (ij % 3) * 3;
            short8 na0, na1;
            if (!(ij == 8 && ct == Cc - 32)) {
                int nij = (ij == 8) ? 0 : ij + 1;
                int nct = (ij == 8) ? ct + 32 : ct;
                na0 = ALOAD(nij, nct, 0);
                na1 = ALOAD(nij, nct, 1);
            }
#pragma unroll
            for (int f = 0; f < 7; f++) {
                int r = sp0[f] + dsp;
                short8 b = *(const short8*)(&Bs[r * 32 + ((quad ^ ((r >> 1) & 3)) << 3)]);
                acc[0][f] = __builtin_amdgcn_mfma_f32_16x16x32_bf16(ca0, b, acc[0][f], 0, 0, 0);
                acc[1][f] = __builtin_amdgcn_mfma_f32_16x16x32_bf16(ca1, b, acc[1][f], 0, 0, 0);
            }
            ca0 = na0;
            ca1 = na1;
        }
    }
#undef ALOAD

    ushort* t7n = t7b + (size_t)n * CHW;
    int sBase = hb * 224 + wsx;
#pragma unroll
    for (int m = 0; m < 2; m++) {
        int obase = o0 + wo + m * 16 + quad * 4;
#pragma unroll
        for (int f = 0; f < 7; f++) {
            int s = sBase + f * 16 + ln15;
#pragma unroll
            for (int r = 0; r < 4; r++)
                t7n[(size_t)(obase + r) * HW + s] = f2bf(acc[m][f][r]);
        }
    }
}

// ---------- t17b = bf16(t3 - w15 @ roll(x,+1,h)); B staged from xpT (bf16)
__global__ __launch_bounds__(256) void k_gemm_t15_mfma(const ushort* __restrict__ xpT,
                                                       const ushort* __restrict__ w15b,
                                                       const ushort* __restrict__ t3b,
                                                       ushort* __restrict__ t17b) {
    __shared__ __align__(16) ushort As[128][40];
    __shared__ __align__(16) ushort Bs[128][40];
    int tid = threadIdx.x;
    int lane = tid & 63;
    int ln15 = lane & 15;
    int quad = lane >> 4;
    int wave = tid >> 6;
    int wm64 = (wave >> 1) * 64;
    int wn64 = (wave & 1) * 64;
    int n = blockIdx.z;
    int s0 = blockIdx.x * 128;
    int o0 = blockIdx.y * 128;
    const ushort* xT = xpT + (size_t)n * (XPLANE * Cc);

    int sp_src[2];
#pragma unroll
    for (int e = 0; e < 2; e++) {
        int s_l = (tid + e * 256) >> 2;
        int s = s0 + s_l;
        int sc = s < HW ? s : HW - 1;
        int h = sc / Ww, w = sc - h * Ww;
        int hp = (h == 0) ? 58 : h + 2;      // roll(x,+1,h): src row h-1, +3 pad
        sp_src[e] = hp * 62 + w + 3;
    }
    int chq = (tid & 3) * 8;

    floatx4 acc[4][4] = {};

    for (int kt = 0; kt < Cc; kt += 32) {
#pragma unroll
        for (int e = 0; e < 2; e++) {
            int lin = tid + e * 256;
            int m = lin >> 2, kq = (lin & 3) * 8;
            *(u16x8*)(&As[m][kq]) =
                *(const u16x8*)(w15b + (size_t)(o0 + m) * Cc + kt + kq);
        }
#pragma unroll
        for (int e = 0; e < 2; e++) {
            int s_l = (tid + e * 256) >> 2;
            *(u16x8*)(&Bs[s_l][chq]) =
                *(const u16x8*)(xT + (size_t)sp_src[e] * Cc + kt + chq);
        }
        __syncthreads();

        short8 af[4], bf[4];
#pragma unroll
        for (int a = 0; a < 4; a++)
            af[a] = *(const short8*)(&As[wm64 + a * 16 + ln15][quad * 8]);
#pragma unroll
        for (int b = 0; b < 4; b++)
            bf[b] = *(const short8*)(&Bs[wn64 + b * 16 + ln15][quad * 8]);
#pragma unroll
        for (int a = 0; a < 4; a++)
#pragma unroll
            for (int b = 0; b < 4; b++)
                acc[a][b] = __builtin_amdgcn_mfma_f32_16x16x32_bf16(
                    af[a], bf[b], acc[a][b], 0, 0, 0);
        __syncthreads();
    }

    const ushort* t3n = t3b + (size_t)n * CHW;
    ushort* t17n = t17b + (size_t)n * CHW;
#pragma unroll
    for (int a = 0; a < 4; a++) {
        int obase = o0 + wm64 + a * 16 + quad * 4;
#pragma unroll
        for (int b = 0; b < 4; b++) {
            int s = s0 + wn64 + b * 16 + ln15;
            if (s < HW) {
#pragma unroll
                for (int r = 0; r < 4; r++) {
                    size_t idx = (size_t)(obase + r) * HW + s;
                    t17n[idx] = f2bf(bf2f(t3n[idx]) - acc[a][b][r]);
                }
            }
        }
    }
}

// ----- merged: t8 += s_hw*t5·t3^T  and  uu += t17·p16^T  (split-K=7, atomics)
__global__ __launch_bounds__(256) void k_abt2(const ushort* __restrict__ t5b,
                                              const ushort* __restrict__ t3b,
                                              const ushort* __restrict__ t17b,
                                              const ushort* __restrict__ p16b,
                                              float* __restrict__ t8,
                                              float* __restrict__ uu) {
    __shared__ __align__(16) ushort As[128][40];
    __shared__ __align__(16) ushort Bs[128][40];
    int tid = threadIdx.x;
    int lane = tid & 63;
    int ln15 = lane & 15;
    int quad = lane >> 4;
    int wave = tid >> 6;
    int wm64 = (wave >> 1) * 64;
    int wn64 = (wave & 1) * 64;
    int sel = blockIdx.y >> 1;
    int c0 = (blockIdx.y & 1) * 128;
    int d0 = blockIdx.x * 128;
    int z = blockIdx.z;
    int n = z / 7, ks = z - n * 7;
    const ushort* An = (sel ? t17b : t5b) + (size_t)n * CHW;
    const ushort* Bb = sel ? p16b : (t3b + (size_t)n * CHW);
    float* outp = (sel ? uu : t8) + (size_t)n * (Cc * Cc);
    float scale = sel ? 1.0f : S_HW;

    floatx4 acc[4][4] = {};
    int kbeg = ks * 448;

    for (int kt = kbeg; kt < kbeg + 448; kt += 32) {
#pragma unroll
        for (int e = 0; e < 2; e++) {
            int lin = tid + e * 256;
            int m = lin >> 2, kq = (lin & 3) * 8;
            *(u16x8*)(&As[m][kq]) =
                *(const u16x8*)(An + (size_t)(c0 + m) * HW + kt + kq);
            *(u16x8*)(&Bs[m][kq]) =
                *(const u16x8*)(Bb + (size_t)(d0 + m) * HW + kt + kq);
        }
        __syncthreads();

        short8 af[4], bf[4];
#pragma unroll
        for (int a = 0; a < 4; a++)
            af[a] = *(const short8*)(&As[wm64 + a * 16 + ln15][quad * 8]);
#pragma unroll
        for (int b = 0; b < 4; b++)
            bf[b] = *(const short8*)(&Bs[wn64 + b * 16 + ln15][quad * 8]);
#pragma unroll
        for (int a = 0; a < 4; a++)
#pragma unroll
            for (int b = 0; b < 4; b++)
                acc[a][b] = __builtin_amdgcn_mfma_f32_16x16x32_bf16(
                    af[a], bf[b], acc[a][b], 0, 0, 0);
        __syncthreads();
    }

#pragma unroll
    for (int a = 0; a < 4; a++) {
        int cbase = c0 + wm64 + a * 16 + quad * 4;
#pragma unroll
        for (int b = 0; b < 4; b++) {
            int d = d0 + wn64 + b * 16 + ln15;
#pragma unroll
            for (int r = 0; r < 4; r++)
                atomicAdd(&outp[(size_t)(cbase + r) * Cc + d], acc[a][b][r] * scale);
        }
    }
}

// computes T[c][d] = s_hw * sum_b u[c][b]*t8[b][d], stores bf16 at [d][c]
__global__ __launch_bounds__(256) void k_gemm_t19(const float* __restrict__ u,
                                                  const float* __restrict__ t8,
                                                  ushort* __restrict__ t19Tb) {
    __shared__ float As[64][20];
    __shared__ float Bs[16][68];
    int tid = threadIdx.x;
    int tx = tid & 15, ty = tid >> 4;
    int n = blockIdx.z;
    int d0 = blockIdx.x * 64;
    int c0 = blockIdx.y * 64;
    const float* un = u + (size_t)n * Cc * Cc;
    const float* t8n = t8 + (size_t)n * Cc * Cc;
    f4 acc[4] = {};
    for (int kt = 0; kt < Cc; kt += 16) {
        int lin = tid * 4;
        {
            int r = lin >> 4, kq = lin & 15;
            *(f4*)(&As[r][kq]) = *(const f4*)(un + (size_t)(c0 + r) * Cc + kt + kq);
        }
        {
            int kk = lin >> 6, col = lin & 63;
            *(f4*)(&Bs[kk][col]) = *(const f4*)(t8n + (size_t)(kt + kk) * Cc + d0 + col);
        }
        __syncthreads();
#pragma unroll
        for (int kk = 0; kk < 16; kk += 4) {
            f4 av[4], bv[4];
#pragma unroll
            for (int a = 0; a < 4; a++) av[a] = *(const f4*)(&As[ty * 4 + a][kk]);
#pragma unroll
            for (int q = 0; q < 4; q++) bv[q] = *(const f4*)(&Bs[kk + q][tx * 4]);
#pragma unroll
            for (int a = 0; a < 4; a++)
#pragma unroll
                for (int q = 0; q < 4; q++) acc[a] += av[a][q] * bv[q];
        }
        __syncthreads();
    }
    ushort* on = t19Tb + (size_t)n * Cc * Cc;
#pragma unroll
    for (int a = 0; a < 4; a++) {
        int c = c0 + ty * 4 + a;
#pragma unroll
        for (int j = 0; j < 4; j++)
            on[(size_t)(d0 + tx * 4 + j) * Cc + c] = f2bf(acc[a][j] * S_HW);
    }
}

// -------- t11[n,s] = sum_b p11[b]*p9[b,s]*(sum_c w6[b,c]*t3[n,c,s])  (bf16 t3)
__global__ __launch_bounds__(256) void k_t11(const ushort* __restrict__ t3b,
                                             const float* __restrict__ w6,
                                             const float* __restrict__ p9,
                                             const float* __restrict__ p11,
                                             float* __restrict__ t11) {
    __shared__ float smem[8704];
    float* w6s = smem;
    float* part = smem;
    float* part2 = smem + 8448;
    int tid = threadIdx.x;
    for (int i = tid; i < C8 * Cc; i += 256) w6s[i] = w6[i];
    __syncthreads();
    int n = blockIdx.y;
    int sl = tid & 63;
    int cg = tid >> 6;
    int s = blockIdx.x * 64 + sl;
    const ushort* t3n = t3b + (size_t)n * CHW + s;
    float acc[C8] = {};
    for (int c = cg * 64; c < cg * 64 + 64; c += 4) {
        float v0 = bf2f(t3n[(c + 0) * HW]);
        float v1 = bf2f(t3n[(c + 1) * HW]);
        float v2 = bf2f(t3n[(c + 2) * HW]);
        float v3 = bf2f(t3n[(c + 3) * HW]);
#pragma unroll
        for (int b = 0; b < C8; b++) {
            f4 wv = *(const f4*)(&w6s[b * Cc + c]);
            acc[b] += wv[0] * v0 + wv[1] * v1 + wv[2] * v2 + wv[3] * v3;
        }
    }
    __syncthreads();
#pragma unroll
    for (int b = 0; b < C8; b++) part[(cg * 64 + sl) * 33 + b] = acc[b];
    __syncthreads();
    float r = 0.f;
#pragma unroll
    for (int j = 0; j < 8; j++) {
        int b = cg * 8 + j;
        float sum = part[(0 * 64 + sl) * 33 + b] + part[(1 * 64 + sl) * 33 + b] +
                    part[(2 * 64 + sl) * 33 + b] + part[(3 * 64 + sl) * 33 + b];
        r += p11[b] * p9[b * HW + s] * sum;
    }
    part2[cg * 64 + sl] = r;
    __syncthreads();
    if (tid < 64)
        t11[(size_t)n * HW + s] = part2[sl] + part2[64 + sl] + part2[128 + sl] + part2[192 + sl];
}

// ------- t13b = bf16(t11 - depthwise_conv(max(t5,t7), w12))  — vec x4
__global__ __launch_bounds__(256) void k_t13(const ushort* __restrict__ t5b,
                                             const ushort* __restrict__ t7b,
                                             const float* __restrict__ t11,
                                             const float* __restrict__ w12,
                                             ushort* __restrict__ t13b) {
    int g = blockIdx.x * 256 + threadIdx.x;   // over N*C*HW/4
    int idx = g * 4;
    int nc = idx / HW;
    int s = idx - nc * HW;
    int c = nc & 255;
    int n = nc >> 8;
    int h = s / Ww, w = s - h * Ww;
    f4 sum = {0.f, 0.f, 0.f, 0.f};
#pragma unroll
    for (int kh = 0; kh < 3; kh++) {
        int hh = h - 2 + 2 * kh;
        if ((unsigned)hh < (unsigned)Hh) {
            size_t base = (size_t)nc * HW + hh * Ww + w;
            u16x4 t5v = *(const u16x4*)(t5b + base);
            u16x4 t7v = *(const u16x4*)(t7b + base);
            float wk = w12[c * 3 + kh];
#pragma unroll
            for (int j = 0; j < 4; j++)
                sum[j] += wk * fmaxf(bf2f(t5v[j]), bf2f(t7v[j]));
        }
    }
    f4 t11v = *(const f4*)(t11 + (size_t)n * HW + s);
    u16x4 o = { f2bf(t11v[0] - sum[0]), f2bf(t11v[1] - sum[1]),
                f2bf(t11v[2] - sum[2]), f2bf(t11v[3] - sum[3]) };
    *(u16x4*)(t13b + idx) = o;
}

// -------- out[c,s] = s_c * sum_d t19T[c,d]*t13[d,s] + t7*t17 — bf16 MFMA
__global__ __launch_bounds__(256) void k_gemm_out_mfma(const ushort* __restrict__ t19Tb,
                                                       const ushort* __restrict__ t13b,
                                                       const ushort* __restrict__ t7b,
                                                       const ushort* __restrict__ t17b,
                                                       float* __restrict__ outp) {
    __shared__ __align__(16) ushort As[128][40];
    __shared__ __align__(16) ushort Bs[128][40];
    int tid = threadIdx.x;
    int lane = tid & 63;
    int ln15 = lane & 15;
    int quad = lane >> 4;
    int wave = tid >> 6;
    int wm64 = (wave >> 1) * 64;
    int wn64 = (wave & 1) * 64;
    int n = blockIdx.z;
    int s0 = blockIdx.x * 128;
    int c0 = blockIdx.y * 128;
    const ushort* An = t19Tb + (size_t)n * Cc * Cc;
    const ushort* t13n = t13b + (size_t)n * CHW;

    floatx4 acc[4][4] = {};

    for (int kt = 0; kt < Cc; kt += 32) {
#pragma unroll
        for (int e = 0; e < 2; e++) {
            int lin = tid + e * 256;
            int m = lin >> 2, kq = (lin & 3) * 8;
            *(u16x8*)(&As[m][kq]) =
                *(const u16x8*)(An + (size_t)(c0 + m) * Cc + kt + kq);
        }
#pragma unroll
        for (int e = 0; e < 2; e++) {
            int lin = tid + e * 256;
            int d_l = lin >> 4;
            int s8 = (lin & 15) * 8;
            int s = s0 + s8;
            int sc = s <= HW - 8 ? s : HW - 8;
            u16x8 v = *(const u16x8*)(t13n + (size_t)(kt + d_l) * HW + sc);
#pragma unroll
            for (int j = 0; j < 8; j++) Bs[s8 + j][d_l] = v[j];
        }
        __syncthreads();

        short8 af[4], bf[4];
#pragma unroll
        for (int a = 0; a < 4; a++)
            af[a] = *(const short8*)(&As[wm64 + a * 16 + ln15][quad * 8]);
#pragma unroll
        for (int b = 0; b < 4; b++)
            bf[b] = *(const short8*)(&Bs[wn64 + b * 16 + ln15][quad * 8]);
#pragma unroll
        for (int a = 0; a < 4; a++)
#pragma unroll
            for (int b = 0; b < 4; b++)
                acc[a][b] = __builtin_amdgcn_mfma_f32_16x16x32_bf16(
                    af[a], bf[b], acc[a][b], 0, 0, 0);
        __syncthreads();
    }

    const ushort* t7n = t7b + (size_t)n * CHW;
    const ushort* t17n = t17b + (size_t)n * CHW;
    float* on = outp + (size_t)n * CHW;
#pragma unroll
    for (int a = 0; a < 4; a++) {
        int cbase = c0 + wm64 + a * 16 + quad * 4;
#pragma unroll
        for (int b = 0; b < 4; b++) {
            int s = s0 + wn64 + b * 16 + ln15;
            if (s < HW) {
#pragma unroll
                for (int r = 0; r < 4; r++) {
                    size_t idx = (size_t)(cbase + r) * HW + s;
                    on[idx] = acc[a][b][r] * S_C + bf2f(t7n[idx]) * bf2f(t17n[idx]);
                }
            }
        }
    }
}

extern "C" void kernel_launch(void* const* d_in, const int* in_sizes, int n_in,
                              void* d_out, int out_size, void* d_ws, size_t ws_size,
                              hipStream_t stream) {
    const float* x   = (const float*)d_in[0];
    const float* p2  = (const float*)d_in[1];
    const float* w6  = (const float*)d_in[2];
    const float* w7  = (const float*)d_in[3];
    const float* p9  = (const float*)d_in[4];
    const float* p11 = (const float*)d_in[5];
    const float* w12 = (const float*)d_in[6];
    const float* w15 = (const float*)d_in[7];
    const float* p16 = (const float*)d_in[8];
    float* ws = (float*)d_ws;

    float* t8  = ws;                        // 524288
    float* uu  = ws + 524288;               // 524288
    float* t11 = ws + 1048576;              // 25600
    ushort* ub  = (ushort*)(ws + 1081344);
    ushort* t5b   = ub;                     // 6422528
    ushort* t3b   = ub + 6422528;           // 6422528
    ushort* t17b  = ub + 12845056;          // 6422528
    ushort* t13b  = ub + 19267584;          // 6422528
    ushort* t7b   = ub + 25690112;          // 6422528
    ushort* xpT   = ub + 32112640;          // 7872512
    ushort* w7p   = ub + 39985152;          // 589824
    ushort* w15b  = ub + 40574976;          // 65536
    ushort* p16b  = ub + 40640512;          // 802816
    ushort* t19Tb = ub + 41443328;          // 524288
    float* outp = (float*)d_out;

    hipMemsetAsync(xpT, 0, (size_t)XPAD_ELEMS * 2, stream);
    k_t3sm<<<dim3(Nn * Cc), dim3(256), 0, stream>>>(x, p2, t3b, t5b);
    k_xT<<<dim3(28, 8, Nn), dim3(256), 0, stream>>>(x, xpT);
    k_prep<<<dim3(5696), dim3(256), 0, stream>>>(w7, w15, p16, w7p, w15b, p16b);
    hipMemsetAsync(t8, 0, (size_t)Nn * Cc * Cc * 4, stream);
    hipMemsetAsync(uu, 0, (size_t)Nn * Cc * Cc * 4, stream);
    k_gemm_t7_mfma<<<dim3(4, 14, Nn), dim3(256), 0, stream>>>(xpT, w7p, t7b);
    k_gemm_t15_mfma<<<dim3(25, 2, Nn), dim3(256), 0, stream>>>(xpT, w15b, t3b, t17b);
    k_abt2<<<dim3(2, 4, Nn * 7), dim3(256), 0, stream>>>(t5b, t3b, t17b, p16b, t8, uu);
    k_t11<<<dim3(49, Nn), dim3(256), 0, stream>>>(t3b, w6, p9, p11, t11);
    k_gemm_t19<<<dim3(4, 4, Nn), dim3(256), 0, stream>>>(uu, t8, t19Tb);
    k_t13<<<dim3(6272), dim3(256), 0, stream>>>(t5b, t7b, t11, w12, t13b);
    k_gemm_out_mfma<<<dim3(25, 2, Nn), dim3(256), 0, stream>>>(t19Tb, t13b, t7b, t17b, outp);
}

// Round 8
// 312.641 us; speedup vs baseline: 1.2283x; 1.2283x over previous
//
#include <hip/hip_runtime.h>

#define Nn 8
#define Cc 256
#define C8 32
#define Hh 56
#define Ww 56
#define HW 3136
#define CHW (Cc * HW)          // 802816
#define K9C 2304
#define S_HW (1.0f / 56.0f)    // 1/sqrt(H*W)
#define S_C  0.0625f           // 1/sqrt(C)
#define XPLANE 3844            // 62*62 padded plane
#define XPAD_ELEMS (Nn * XPLANE * Cc)

typedef float f4 __attribute__((ext_vector_type(4)));
typedef unsigned short ushort;
typedef __attribute__((ext_vector_type(4))) unsigned short u16x4;
typedef __attribute__((ext_vector_type(8))) unsigned short u16x8;
typedef __attribute__((ext_vector_type(8))) short short8;   // bf16 MFMA frag
typedef __attribute__((ext_vector_type(4))) float floatx4;

__device__ __forceinline__ ushort f2bf(float f) {   // RNE
    union { float f; unsigned u; } v; v.f = f;
    unsigned r = v.u + 0x7FFF + ((v.u >> 16) & 1);
    return (ushort)(r >> 16);
}
__device__ __forceinline__ float bf2f(ushort u) {
    union { unsigned u; float f; } v; v.u = ((unsigned)u) << 16;
    return v.f;
}

// ---- fused: t3 = (p2*x)^2 (bf16 out) + t5 = softmax_h(roll(t3,+1h,-1w)) (bf16)
__global__ __launch_bounds__(256) void k_t3sm(const float* __restrict__ x,
                                              const float* __restrict__ p2,
                                              ushort* __restrict__ t3b,
                                              ushort* __restrict__ t5b) {
    __shared__ float ld[HW];
    __shared__ float mx[Ww], rs[Ww];
    int tid = threadIdx.x;
    int nc = blockIdx.x;                 // n*C + c
    int c = nc & 255;
    const float* xn = x + (size_t)nc * HW;
    const float* pp = p2 + (size_t)c * HW;
    ushort* t3n = t3b + (size_t)nc * HW;
    for (int i = tid; i < 784; i += 256) {
        f4 xv = *(const f4*)(xn + i * 4);
        f4 pv = *(const f4*)(pp + i * 4);
        f4 t = xv * pv;
        f4 q = t * t;
        *(f4*)(&ld[i * 4]) = q;
        u16x4 qb = { f2bf(q[0]), f2bf(q[1]), f2bf(q[2]), f2bf(q[3]) };
        *(u16x4*)(t3n + i * 4) = qb;
    }
    __syncthreads();
    if (tid < Ww) {
        float m = -1e30f;
        for (int h = 0; h < Hh; h++) m = fmaxf(m, ld[h * Ww + tid]);
        float s = 0.f;
        for (int h = 0; h < Hh; h++) s += __expf(ld[h * Ww + tid] - m);
        mx[tid] = m;
        rs[tid] = 1.0f / s;
    }
    __syncthreads();
    ushort* dst = t5b + (size_t)nc * HW;
    for (int i = tid; i < HW; i += 256) {
        int h = i / Ww, w = i - h * Ww;
        int wp = (w + 1 == Ww) ? 0 : w + 1;
        int hp = (h == 0) ? Hh - 1 : h - 1;
        dst[i] = f2bf(__expf(ld[hp * Ww + wp] - mx[wp]) * rs[wp]);
    }
}

// ------- xpT[n][(h+3)*62+(w+3)][c] = bf16(x[n][c][h][w])  (padded transpose)
__global__ __launch_bounds__(256) void k_xT(const float* __restrict__ x,
                                            ushort* __restrict__ xpT) {
    __shared__ ushort Ts[112][40];
    int tid = threadIdx.x;
    int n = blockIdx.z;
    int c0 = blockIdx.y * 32;
    int s0 = blockIdx.x * 112;          // 2 exact h-rows
    const float* xn = x + (size_t)n * CHW;
#pragma unroll
    for (int e = 0; e < 4; e++) {
        int lin = tid + e * 256;
        int sq = lin & 31;
        int c_l = lin >> 5;
        if (sq < 28) {
            f4 v = *(const f4*)(xn + (size_t)(c0 + c_l) * HW + s0 + sq * 4);
#pragma unroll
            for (int k = 0; k < 4; k++) Ts[sq * 4 + k][c_l] = f2bf(v[k]);
        }
    }
    __syncthreads();
    ushort* dstn = xpT + (size_t)n * (XPLANE * Cc);
#pragma unroll
    for (int e = 0; e < 2; e++) {
        int lin = tid + e * 256;
        int r = lin >> 2, ch = lin & 3;
        if (r < 112) {
            u16x8 v = *(const u16x8*)(&Ts[r][ch * 8]);
            int s_g = s0 + r;
            int h = s_g / 56;
            int wc = s_g - h * 56;
            size_t drow = (size_t)((h + 3) * 62 + wc + 3);
            *(u16x8*)(dstn + drow * Cc + c0 + ch * 8) = v;
        }
    }
}

// -------- merged prep: w7p permute + w15/p16 bf16 converts
__global__ __launch_bounds__(256) void k_prep(const float* __restrict__ w7,
                                              const float* __restrict__ w15,
                                              const float* __restrict__ p16,
                                              ushort* __restrict__ w7p,
                                              ushort* __restrict__ w15b,
                                              ushort* __restrict__ p16b) {
    int g = blockIdx.x * 256 + threadIdx.x;
    if (g < 589824) {                    // w7p[ij][o][c] = w7[o][c*9+ij]
        int ij = g >> 16;
        int rem = g & 65535;
        int o = rem >> 8;
        int c = rem & 255;
        w7p[g] = f2bf(w7[(size_t)o * K9C + c * 9 + ij]);
    } else if (g < 655360) {
        int i = g - 589824;
        w15b[i] = f2bf(w15[i]);
    } else {
        int i = g - 655360;
        if (i < 802816) p16b[i] = f2bf(p16[i]);
    }
}

// --------------- t7b = bf16(w7 @ im2col(x)) as 9 shifted GEMMs over xpT
// B window staged via global_load_lds (16B DMA, no VGPR round-trip) into
// stride-32 rows (DMA writes lane-contiguous; ds_reads 2-way = free).
// A loaded fresh per ij from w7p (L2-resident) — R5-proven pattern.
__global__ __launch_bounds__(256, 3) void k_gemm_t7_mfma(
        const ushort* __restrict__ xpT,
        const ushort* __restrict__ w7p,
        ushort* __restrict__ t7b) {
    __shared__ __align__(16) ushort Bs[640 * 32];   // 40 KB
    int tid = threadIdx.x;
    int lane = tid & 63;
    int ln15 = lane & 15, quad = lane >> 4;
    int wave = tid >> 6;
    int wo = (wave >> 1) * 32;
    int wsx = (wave & 1) * 112;
    int n = blockIdx.z;
    int hb = blockIdx.y;                 // 0..13
    int o0 = blockIdx.x * 64;
    const ushort* stagePtr = xpT + (size_t)n * (XPLANE * Cc) + (size_t)(hb * 248) * Cc;

    int sp0[7];
#pragma unroll
    for (int f = 0; f < 7; f++) {
        int s_l = wsx + f * 16 + ln15;
        int orow = s_l / 56;
        int wv = s_l - orow * 56;
        sp0[f] = orow * 62 + wv;
    }

    floatx4 acc[2][7] = {};

    for (int ct = 0; ct < Cc; ct += 32) {
        // ---- stage B window: 2480 (pad 2560) 16B DMA chunks, lds = base+lane*16
#pragma unroll
        for (int e = 0; e < 10; e++) {
            int lin = tid + e * 256;
            int row = lin >> 2;
            row = row > 619 ? 619 : row;           // pad rows never read
            const ushort* gp = stagePtr + (size_t)row * Cc + ct + (lin & 3) * 8;
            int lofs = __builtin_amdgcn_readfirstlane(((tid & ~63) + e * 256) * 16);
            __builtin_amdgcn_global_load_lds(
                (const __attribute__((address_space(1))) unsigned int*)gp,
                (__attribute__((address_space(3))) unsigned int*)((char*)Bs + lofs),
                16, 0, 0);
        }
        __syncthreads();                           // drains vmcnt + barrier

        const ushort* wp = w7p + ct + quad * 8;
#pragma unroll
        for (int ij = 0; ij < 9; ij++) {
            int dsp = (ij / 3) * 186 + (ij % 3) * 3;
            short8 a0 = *(const short8*)(wp + (size_t)(ij * 256 + o0 + wo + ln15) * Cc);
            short8 a1 = *(const short8*)(wp + (size_t)(ij * 256 + o0 + wo + 16 + ln15) * Cc);
#pragma unroll
            for (int f = 0; f < 7; f++) {
                int r = sp0[f] + dsp;
                short8 b = *(const short8*)(&Bs[r * 32 + quad * 8]);
                acc[0][f] = __builtin_amdgcn_mfma_f32_16x16x32_bf16(a0, b, acc[0][f], 0, 0, 0);
                acc[1][f] = __builtin_amdgcn_mfma_f32_16x16x32_bf16(a1, b, acc[1][f], 0, 0, 0);
            }
        }
        __syncthreads();                           // Bs safe to overwrite
    }

    ushort* t7n = t7b + (size_t)n * CHW;
    int sBase = hb * 224 + wsx;
#pragma unroll
    for (int m = 0; m < 2; m++) {
        int obase = o0 + wo + m * 16 + quad * 4;
#pragma unroll
        for (int f = 0; f < 7; f++) {
            int s = sBase + f * 16 + ln15;
#pragma unroll
            for (int r = 0; r < 4; r++)
                t7n[(size_t)(obase + r) * HW + s] = f2bf(acc[m][f][r]);
        }
    }
}

// ---------- t17b = bf16(t3 - w15 @ roll(x,+1,h)); B staged from xpT (bf16)
__global__ __launch_bounds__(256) void k_gemm_t15_mfma(const ushort* __restrict__ xpT,
                                                       const ushort* __restrict__ w15b,
                                                       const ushort* __restrict__ t3b,
                                                       ushort* __restrict__ t17b) {
    __shared__ __align__(16) ushort As[128][40];
    __shared__ __align__(16) ushort Bs[128][40];
    int tid = threadIdx.x;
    int lane = tid & 63;
    int ln15 = lane & 15;
    int quad = lane >> 4;
    int wave = tid >> 6;
    int wm64 = (wave >> 1) * 64;
    int wn64 = (wave & 1) * 64;
    int n = blockIdx.z;
    int s0 = blockIdx.x * 128;
    int o0 = blockIdx.y * 128;
    const ushort* xT = xpT + (size_t)n * (XPLANE * Cc);

    int sp_src[2];
#pragma unroll
    for (int e = 0; e < 2; e++) {
        int s_l = (tid + e * 256) >> 2;
        int s = s0 + s_l;
        int sc = s < HW ? s : HW - 1;
        int h = sc / Ww, w = sc - h * Ww;
        int hp = (h == 0) ? 58 : h + 2;      // roll(x,+1,h): src row h-1, +3 pad
        sp_src[e] = hp * 62 + w + 3;
    }
    int chq = (tid & 3) * 8;

    floatx4 acc[4][4] = {};

    for (int kt = 0; kt < Cc; kt += 32) {
#pragma unroll
        for (int e = 0; e < 2; e++) {
            int lin = tid + e * 256;
            int m = lin >> 2, kq = (lin & 3) * 8;
            *(u16x8*)(&As[m][kq]) =
                *(const u16x8*)(w15b + (size_t)(o0 + m) * Cc + kt + kq);
        }
#pragma unroll
        for (int e = 0; e < 2; e++) {
            int s_l = (tid + e * 256) >> 2;
            *(u16x8*)(&Bs[s_l][chq]) =
                *(const u16x8*)(xT + (size_t)sp_src[e] * Cc + kt + chq);
        }
        __syncthreads();

        short8 af[4], bf[4];
#pragma unroll
        for (int a = 0; a < 4; a++)
            af[a] = *(const short8*)(&As[wm64 + a * 16 + ln15][quad * 8]);
#pragma unroll
        for (int b = 0; b < 4; b++)
            bf[b] = *(const short8*)(&Bs[wn64 + b * 16 + ln15][quad * 8]);
#pragma unroll
        for (int a = 0; a < 4; a++)
#pragma unroll
            for (int b = 0; b < 4; b++)
                acc[a][b] = __builtin_amdgcn_mfma_f32_16x16x32_bf16(
                    af[a], bf[b], acc[a][b], 0, 0, 0);
        __syncthreads();
    }

    const ushort* t3n = t3b + (size_t)n * CHW;
    ushort* t17n = t17b + (size_t)n * CHW;
#pragma unroll
    for (int a = 0; a < 4; a++) {
        int obase = o0 + wm64 + a * 16 + quad * 4;
#pragma unroll
        for (int b = 0; b < 4; b++) {
            int s = s0 + wn64 + b * 16 + ln15;
            if (s < HW) {
#pragma unroll
                for (int r = 0; r < 4; r++) {
                    size_t idx = (size_t)(obase + r) * HW + s;
                    t17n[idx] = f2bf(bf2f(t3n[idx]) - acc[a][b][r]);
                }
            }
        }
    }
}

// ----- merged: t8 += s_hw*t5·t3^T  and  uu += t17·p16^T  (split-K=7, atomics)
__global__ __launch_bounds__(256) void k_abt2(const ushort* __restrict__ t5b,
                                              const ushort* __restrict__ t3b,
                                              const ushort* __restrict__ t17b,
                                              const ushort* __restrict__ p16b,
                                              float* __restrict__ t8,
                                              float* __restrict__ uu) {
    __shared__ __align__(16) ushort As[128][40];
    __shared__ __align__(16) ushort Bs[128][40];
    int tid = threadIdx.x;
    int lane = tid & 63;
    int ln15 = lane & 15;
    int quad = lane >> 4;
    int wave = tid >> 6;
    int wm64 = (wave >> 1) * 64;
    int wn64 = (wave & 1) * 64;
    int sel = blockIdx.y >> 1;
    int c0 = (blockIdx.y & 1) * 128;
    int d0 = blockIdx.x * 128;
    int z = blockIdx.z;
    int n = z / 7, ks = z - n * 7;
    const ushort* An = (sel ? t17b : t5b) + (size_t)n * CHW;
    const ushort* Bb = sel ? p16b : (t3b + (size_t)n * CHW);
    float* outp = (sel ? uu : t8) + (size_t)n * (Cc * Cc);
    float scale = sel ? 1.0f : S_HW;

    floatx4 acc[4][4] = {};
    int kbeg = ks * 448;

    for (int kt = kbeg; kt < kbeg + 448; kt += 32) {
#pragma unroll
        for (int e = 0; e < 2; e++) {
            int lin = tid + e * 256;
            int m = lin >> 2, kq = (lin & 3) * 8;
            *(u16x8*)(&As[m][kq]) =
                *(const u16x8*)(An + (size_t)(c0 + m) * HW + kt + kq);
            *(u16x8*)(&Bs[m][kq]) =
                *(const u16x8*)(Bb + (size_t)(d0 + m) * HW + kt + kq);
        }
        __syncthreads();

        short8 af[4], bf[4];
#pragma unroll
        for (int a = 0; a < 4; a++)
            af[a] = *(const short8*)(&As[wm64 + a * 16 + ln15][quad * 8]);
#pragma unroll
        for (int b = 0; b < 4; b++)
            bf[b] = *(const short8*)(&Bs[wn64 + b * 16 + ln15][quad * 8]);
#pragma unroll
        for (int a = 0; a < 4; a++)
#pragma unroll
            for (int b = 0; b < 4; b++)
                acc[a][b] = __builtin_amdgcn_mfma_f32_16x16x32_bf16(
                    af[a], bf[b], acc[a][b], 0, 0, 0);
        __syncthreads();
    }

#pragma unroll
    for (int a = 0; a < 4; a++) {
        int cbase = c0 + wm64 + a * 16 + quad * 4;
#pragma unroll
        for (int b = 0; b < 4; b++) {
            int d = d0 + wn64 + b * 16 + ln15;
#pragma unroll
            for (int r = 0; r < 4; r++)
                atomicAdd(&outp[(size_t)(cbase + r) * Cc + d], acc[a][b][r] * scale);
        }
    }
}

// computes T[c][d] = s_hw * sum_b u[c][b]*t8[b][d], stores bf16 at [d][c]
__global__ __launch_bounds__(256) void k_gemm_t19(const float* __restrict__ u,
                                                  const float* __restrict__ t8,
                                                  ushort* __restrict__ t19Tb) {
    __shared__ float As[64][20];
    __shared__ float Bs[16][68];
    int tid = threadIdx.x;
    int tx = tid & 15, ty = tid >> 4;
    int n = blockIdx.z;
    int d0 = blockIdx.x * 64;
    int c0 = blockIdx.y * 64;
    const float* un = u + (size_t)n * Cc * Cc;
    const float* t8n = t8 + (size_t)n * Cc * Cc;
    f4 acc[4] = {};
    for (int kt = 0; kt < Cc; kt += 16) {
        int lin = tid * 4;
        {
            int r = lin >> 4, kq = lin & 15;
            *(f4*)(&As[r][kq]) = *(const f4*)(un + (size_t)(c0 + r) * Cc + kt + kq);
        }
        {
            int kk = lin >> 6, col = lin & 63;
            *(f4*)(&Bs[kk][col]) = *(const f4*)(t8n + (size_t)(kt + kk) * Cc + d0 + col);
        }
        __syncthreads();
#pragma unroll
        for (int kk = 0; kk < 16; kk += 4) {
            f4 av[4], bv[4];
#pragma unroll
            for (int a = 0; a < 4; a++) av[a] = *(const f4*)(&As[ty * 4 + a][kk]);
#pragma unroll
            for (int q = 0; q < 4; q++) bv[q] = *(const f4*)(&Bs[kk + q][tx * 4]);
#pragma unroll
            for (int a = 0; a < 4; a++)
#pragma unroll
                for (int q = 0; q < 4; q++) acc[a] += av[a][q] * bv[q];
        }
        __syncthreads();
    }
    ushort* on = t19Tb + (size_t)n * Cc * Cc;
#pragma unroll
    for (int a = 0; a < 4; a++) {
        int c = c0 + ty * 4 + a;
#pragma unroll
        for (int j = 0; j < 4; j++)
            on[(size_t)(d0 + tx * 4 + j) * Cc + c] = f2bf(acc[a][j] * S_HW);
    }
}

// -------- t11[n,s] = sum_b p11[b]*p9[b,s]*(sum_c w6[b,c]*t3[n,c,s])  (bf16 t3)
__global__ __launch_bounds__(256) void k_t11(const ushort* __restrict__ t3b,
                                             const float* __restrict__ w6,
                                             const float* __restrict__ p9,
                                             const float* __restrict__ p11,
                                             float* __restrict__ t11) {
    __shared__ float smem[8704];
    float* w6s = smem;
    float* part = smem;
    float* part2 = smem + 8448;
    int tid = threadIdx.x;
    for (int i = tid; i < C8 * Cc; i += 256) w6s[i] = w6[i];
    __syncthreads();
    int n = blockIdx.y;
    int sl = tid & 63;
    int cg = tid >> 6;
    int s = blockIdx.x * 64 + sl;
    const ushort* t3n = t3b + (size_t)n * CHW + s;
    float acc[C8] = {};
    for (int c = cg * 64; c < cg * 64 + 64; c += 4) {
        float v0 = bf2f(t3n[(c + 0) * HW]);
        float v1 = bf2f(t3n[(c + 1) * HW]);
        float v2 = bf2f(t3n[(c + 2) * HW]);
        float v3 = bf2f(t3n[(c + 3) * HW]);
#pragma unroll
        for (int b = 0; b < C8; b++) {
            f4 wv = *(const f4*)(&w6s[b * Cc + c]);
            acc[b] += wv[0] * v0 + wv[1] * v1 + wv[2] * v2 + wv[3] * v3;
        }
    }
    __syncthreads();
#pragma unroll
    for (int b = 0; b < C8; b++) part[(cg * 64 + sl) * 33 + b] = acc[b];
    __syncthreads();
    float r = 0.f;
#pragma unroll
    for (int j = 0; j < 8; j++) {
        int b = cg * 8 + j;
        float sum = part[(0 * 64 + sl) * 33 + b] + part[(1 * 64 + sl) * 33 + b] +
                    part[(2 * 64 + sl) * 33 + b] + part[(3 * 64 + sl) * 33 + b];
        r += p11[b] * p9[b * HW + s] * sum;
    }
    part2[cg * 64 + sl] = r;
    __syncthreads();
    if (tid < 64)
        t11[(size_t)n * HW + s] = part2[sl] + part2[64 + sl] + part2[128 + sl] + part2[192 + sl];
}

// ------- t13b = bf16(t11 - depthwise_conv(max(t5,t7), w12))  — vec x4
__global__ __launch_bounds__(256) void k_t13(const ushort* __restrict__ t5b,
                                             const ushort* __restrict__ t7b,
                                             const float* __restrict__ t11,
                                             const float* __restrict__ w12,
                                             ushort* __restrict__ t13b) {
    int g = blockIdx.x * 256 + threadIdx.x;   // over N*C*HW/4
    int idx = g * 4;
    int nc = idx / HW;
    int s = idx - nc * HW;
    int c = nc & 255;
    int n = nc >> 8;
    int h = s / Ww, w = s - h * Ww;
    f4 sum = {0.f, 0.f, 0.f, 0.f};
#pragma unroll
    for (int kh = 0; kh < 3; kh++) {
        int hh = h - 2 + 2 * kh;
        if ((unsigned)hh < (unsigned)Hh) {
            size_t base = (size_t)nc * HW + hh * Ww + w;
            u16x4 t5v = *(const u16x4*)(t5b + base);
            u16x4 t7v = *(const u16x4*)(t7b + base);
            float wk = w12[c * 3 + kh];
#pragma unroll
            for (int j = 0; j < 4; j++)
                sum[j] += wk * fmaxf(bf2f(t5v[j]), bf2f(t7v[j]));
        }
    }
    f4 t11v = *(const f4*)(t11 + (size_t)n * HW + s);
    u16x4 o = { f2bf(t11v[0] - sum[0]), f2bf(t11v[1] - sum[1]),
                f2bf(t11v[2] - sum[2]), f2bf(t11v[3] - sum[3]) };
    *(u16x4*)(t13b + idx) = o;
}

// -------- out[c,s] = s_c * sum_d t19T[c,d]*t13[d,s] + t7*t17 — bf16 MFMA
__global__ __launch_bounds__(256) void k_gemm_out_mfma(const ushort* __restrict__ t19Tb,
                                                       const ushort* __restrict__ t13b,
                                                       const ushort* __restrict__ t7b,
                                                       const ushort* __restrict__ t17b,
                                                       float* __restrict__ outp) {
    __shared__ __align__(16) ushort As[128][40];
    __shared__ __align__(16) ushort Bs[128][40];
    int tid = threadIdx.x;
    int lane = tid & 63;
    int ln15 = lane & 15;
    int quad = lane >> 4;
    int wave = tid >> 6;
    int wm64 = (wave >> 1) * 64;
    int wn64 = (wave & 1) * 64;
    int n = blockIdx.z;
    int s0 = blockIdx.x * 128;
    int c0 = blockIdx.y * 128;
    const ushort* An = t19Tb + (size_t)n * Cc * Cc;
    const ushort* t13n = t13b + (size_t)n * CHW;

    floatx4 acc[4][4] = {};

    for (int kt = 0; kt < Cc; kt += 32) {
#pragma unroll
        for (int e = 0; e < 2; e++) {
            int lin = tid + e * 256;
            int m = lin >> 2, kq = (lin & 3) * 8;
            *(u16x8*)(&As[m][kq]) =
                *(const u16x8*)(An + (size_t)(c0 + m) * Cc + kt + kq);
        }
#pragma unroll
        for (int e = 0; e < 2; e++) {
            int lin = tid + e * 256;
            int d_l = lin >> 4;
            int s8 = (lin & 15) * 8;
            int s = s0 + s8;
            int sc = s <= HW - 8 ? s : HW - 8;
            u16x8 v = *(const u16x8*)(t13n + (size_t)(kt + d_l) * HW + sc);
#pragma unroll
            for (int j = 0; j < 8; j++) Bs[s8 + j][d_l] = v[j];
        }
        __syncthreads();

        short8 af[4], bf[4];
#pragma unroll
        for (int a = 0; a < 4; a++)
            af[a] = *(const short8*)(&As[wm64 + a * 16 + ln15][quad * 8]);
#pragma unroll
        for (int b = 0; b < 4; b++)
            bf[b] = *(const short8*)(&Bs[wn64 + b * 16 + ln15][quad * 8]);
#pragma unroll
        for (int a = 0; a < 4; a++)
#pragma unroll
            for (int b = 0; b < 4; b++)
                acc[a][b] = __builtin_amdgcn_mfma_f32_16x16x32_bf16(
                    af[a], bf[b], acc[a][b], 0, 0, 0);
        __syncthreads();
    }

    const ushort* t7n = t7b + (size_t)n * CHW;
    const ushort* t17n = t17b + (size_t)n * CHW;
    float* on = outp + (size_t)n * CHW;
#pragma unroll
    for (int a = 0; a < 4; a++) {
        int cbase = c0 + wm64 + a * 16 + quad * 4;
#pragma unroll
        for (int b = 0; b < 4; b++) {
            int s = s0 + wn64 + b * 16 + ln15;
            if (s < HW) {
#pragma unroll
                for (int r = 0; r < 4; r++) {
                    size_t idx = (size_t)(cbase + r) * HW + s;
                    on[idx] = acc[a][b][r] * S_C + bf2f(t7n[idx]) * bf2f(t17n[idx]);
                }
            }
        }
    }
}

extern "C" void kernel_launch(void* const* d_in, const int* in_sizes, int n_in,
                              void* d_out, int out_size, void* d_ws, size_t ws_size,
                              hipStream_t stream) {
    const float* x   = (const float*)d_in[0];
    const float* p2  = (const float*)d_in[1];
    const float* w6  = (const float*)d_in[2];
    const float* w7  = (const float*)d_in[3];
    const float* p9  = (const float*)d_in[4];
    const float* p11 = (const float*)d_in[5];
    const float* w12 = (const float*)d_in[6];
    const float* w15 = (const float*)d_in[7];
    const float* p16 = (const float*)d_in[8];
    float* ws = (float*)d_ws;

    float* t8  = ws;                        // 524288
    float* uu  = ws + 524288;               // 524288
    float* t11 = ws + 1048576;              // 25600
    ushort* ub  = (ushort*)(ws + 1081344);
    ushort* t5b   = ub;                     // 6422528
    ushort* t3b   = ub + 6422528;           // 6422528
    ushort* t17b  = ub + 12845056;          // 6422528
    ushort* t13b  = ub + 19267584;          // 6422528
    ushort* t7b   = ub + 25690112;          // 6422528
    ushort* xpT   = ub + 32112640;          // 7872512
    ushort* w7p   = ub + 39985152;          // 589824
    ushort* w15b  = ub + 40574976;          // 65536
    ushort* p16b  = ub + 40640512;          // 802816
    ushort* t19Tb = ub + 41443328;          // 524288
    float* outp = (float*)d_out;

    hipMemsetAsync(xpT, 0, (size_t)XPAD_ELEMS * 2, stream);
    k_t3sm<<<dim3(Nn * Cc), dim3(256), 0, stream>>>(x, p2, t3b, t5b);
    k_xT<<<dim3(28, 8, Nn), dim3(256), 0, stream>>>(x, xpT);
    k_prep<<<dim3(5696), dim3(256), 0, stream>>>(w7, w15, p16, w7p, w15b, p16b);
    hipMemsetAsync(t8, 0, (size_t)Nn * Cc * Cc * 4, stream);
    hipMemsetAsync(uu, 0, (size_t)Nn * Cc * Cc * 4, stream);
    k_gemm_t7_mfma<<<dim3(4, 14, Nn), dim3(256), 0, stream>>>(xpT, w7p, t7b);
    k_gemm_t15_mfma<<<dim3(25, 2, Nn), dim3(256), 0, stream>>>(xpT, w15b, t3b, t17b);
    k_abt2<<<dim3(2, 4, Nn * 7), dim3(256), 0, stream>>>(t5b, t3b, t17b, p16b, t8, uu);
    k_t11<<<dim3(49, Nn), dim3(256), 0, stream>>>(t3b, w6, p9, p11, t11);
    k_gemm_t19<<<dim3(4, 4, Nn), dim3(256), 0, stream>>>(uu, t8, t19Tb);
    k_t13<<<dim3(6272), dim3(256), 0, stream>>>(t5b, t7b, t11, w12, t13b);
    k_gemm_out_mfma<<<dim3(25, 2, Nn), dim3(256), 0, stream>>>(t19Tb, t13b, t7b, t17b, outp);
}